// Round 3
// baseline (583.635 us; speedup 1.0000x reference)
//
#include <hip/hip_runtime.h>

#define NN 40000
#define NE 640000
// D = 128; f32 inputs, indices sniffed i32/i64 at runtime

typedef unsigned short u16;
typedef unsigned int u32;
typedef __attribute__((ext_vector_type(4))) float f32x4;
typedef __attribute__((ext_vector_type(4))) float fv4;
typedef __attribute__((ext_vector_type(4))) u32 uv4;
typedef __attribute__((ext_vector_type(8))) __bf16 bf16x8;

#define LSTR 132  // LDS row stride in elements
#define TPW 4     // tiles (16 edges) per wave in edge_gemm

__device__ __forceinline__ float bf2f(u16 u) { return __uint_as_float(((u32)u) << 16); }
__device__ __forceinline__ u16 f2bf(float f) {
  u32 u = __float_as_uint(f);
  u32 r = 0x7fffu + ((u >> 16) & 1u);
  return (u16)((u + r) >> 16);
}
__device__ __forceinline__ float splus(float v) {
  return fmaxf(v, 0.0f) + __logf(1.0f + __expf(-fabsf(v)));
}
__device__ __forceinline__ fv4 ntl4(const float* p) {
  return __builtin_nontemporal_load((const fv4*)p);
}

// ---------- sniff index dtype ----------
__global__ void sniff_k(const u32* __restrict__ gamma, const u32* __restrict__ eidx,
                        u32* __restrict__ flags) {
  if (threadIdx.x == 0) {
    flags[0] = (gamma[0] == 0x3F803F80u) ? 1u : 0u;
    u32 odd = eidx[1] | eidx[3] | eidx[5] | eidx[7] |
              eidx[9] | eidx[11] | eidx[13] | eidx[15];
    flags[1] = (odd == 0u) ? 1u : 0u;  // int64 indices?
  }
}

__device__ __forceinline__ int load_col(const void* eidx, int e, u32 i64) {
  int nc = i64 ? (int)((const u32*)eidx)[2 * ((size_t)NE + e)]
               : ((const int*)eidx)[NE + e];
  return min(max(nc, 0), NN - 1);
}
__device__ __forceinline__ int load_row(const void* eidx, int e, u32 i64) {
  int nr = i64 ? (int)((const u32*)eidx)[2 * (size_t)e]
               : ((const int*)eidx)[e];
  return min(max(nr, 0), NN - 1);
}

// ---------- weights f32 -> bf16 (sg, dg, du, su, eg) ----------
__global__ __launch_bounds__(256) void wconv5_k(
    const float* __restrict__ W0, const float* __restrict__ W1,
    const float* __restrict__ W2, const float* __restrict__ W3,
    const float* __restrict__ W4, u16* __restrict__ out) {
  int i = blockIdx.x * 256 + threadIdx.x;
  int mtx = blockIdx.y;
  const float* W = (mtx == 0) ? W0 : (mtx == 1) ? W1 : (mtx == 2) ? W2
                 : (mtx == 3) ? W3 : W4;
  out[mtx * 16384 + i] = f2bf(W[i]);
}

// ---------- in-degree histogram (deg==0 guard for the gate factor) ----------
__global__ __launch_bounds__(256) void hist_k(const void* __restrict__ eidx,
                                              u32* __restrict__ cnt,
                                              const u32* __restrict__ flags) {
  int e = blockIdx.x * 256 + threadIdx.x;
  atomicAdd(&cnt[load_col(eidx, e, flags[1])], 1u);
}

// ---------- MFMA helpers ----------
__device__ __forceinline__ bf16x8 a_frag(const float* __restrict__ row, int kbase) {
  float4 f0 = *(const float4*)(row + kbase);
  float4 f1 = *(const float4*)(row + kbase + 4);
  bf16x8 a;
  a[0] = (__bf16)f0.x; a[1] = (__bf16)f0.y; a[2] = (__bf16)f0.z; a[3] = (__bf16)f0.w;
  a[4] = (__bf16)f1.x; a[5] = (__bf16)f1.y; a[6] = (__bf16)f1.z; a[7] = (__bf16)f1.w;
  return a;
}

__device__ __forceinline__ bf16x8 cvt8v(fv4 a, fv4 b) {
  bf16x8 r;
  r[0] = (__bf16)a[0]; r[1] = (__bf16)a[1]; r[2] = (__bf16)a[2]; r[3] = (__bf16)a[3];
  r[4] = (__bf16)b[0]; r[5] = (__bf16)b[1]; r[6] = (__bf16)b[2]; r[7] = (__bf16)b[3];
  return r;
}

__device__ __forceinline__ void gemm16(const bf16x8 af[4], const u16* __restrict__ Wb,
                                       const float* __restrict__ bias, int lane,
                                       f32x4 acc[8]) {
  int l15 = lane & 15, lk = lane >> 4;
#pragma unroll
  for (int n = 0; n < 8; ++n) {
    float bv = bias[n * 16 + l15];
    acc[n] = (f32x4){bv, bv, bv, bv};
  }
#pragma unroll
  for (int n = 0; n < 8; ++n) {
    const u16* bp = Wb + (size_t)(n * 16 + l15) * 128 + lk * 8;
#pragma unroll
    for (int k = 0; k < 4; ++k) {
      bf16x8 b = *(const bf16x8*)(bp + 32 * k);
      acc[n] = __builtin_amdgcn_mfma_f32_16x16x32_bf16(af[k], b, acc[n], 0, 0, 0);
    }
  }
}

__device__ __forceinline__ void store_tile(u16* __restrict__ out, int m0, int lane,
                                           const f32x4 acc[8]) {
  int l15 = lane & 15, lk = lane >> 4;
#pragma unroll
  for (int n = 0; n < 8; ++n)
#pragma unroll
    for (int r = 0; r < 4; ++r)
      out[(size_t)(m0 + lk * 4 + r) * 128 + n * 16 + l15] = f2bf(acc[n][r]);
}

// ---------- kernel 1: 4 node GEMMs via MFMA + fused node BN stats ----------
__global__ __launch_bounds__(256) void node_gemm_k(
    const float* __restrict__ x, const u16* __restrict__ Wb,
    const float* __restrict__ B0, const float* __restrict__ B1,
    const float* __restrict__ B2, const float* __restrict__ B3,
    const u32* __restrict__ cnt,
    u16* __restrict__ o0, u16* __restrict__ o1,
    u16* __restrict__ o2, u16* __restrict__ o3,
    float* __restrict__ statsg) {
  __shared__ float red[256];
  int tid = threadIdx.x, lane = tid & 63, w = tid >> 6;
  for (int i = tid; i < 256; i += 256) red[i] = 0.f;
  __syncthreads();
  int m0 = blockIdx.x * 64 + w * 16;
  int l15 = lane & 15, lk = lane >> 4;
  const float* arow = x + (size_t)(m0 + l15) * 128;
  bf16x8 af[4];
#pragma unroll
  for (int k = 0; k < 4; ++k) af[k] = a_frag(arow, 32 * k + 8 * lk);
  f32x4 acc[8], accd[8];
  gemm16(af, Wb + 0 * 16384, B0, lane, acc);  store_tile(o0, m0, lane, acc);
  gemm16(af, Wb + 1 * 16384, B1, lane, acc);  store_tile(o1, m0, lane, acc);
  gemm16(af, Wb + 2 * 16384, B2, lane, accd); store_tile(o2, m0, lane, accd);
  gemm16(af, Wb + 3 * 16384, B3, lane, acc);  store_tile(o3, m0, lane, acc);
  float g[4];
#pragma unroll
  for (int r = 0; r < 4; ++r) g[r] = (cnt[m0 + lk * 4 + r] != 0u) ? 1.0f : 0.0f;
#pragma unroll
  for (int n = 0; n < 8; ++n) {
    float a1 = 0.f, a2 = 0.f;
#pragma unroll
    for (int r = 0; r < 4; ++r) {
      float zv = acc[n][r] + g[r] * accd[n][r];
      a1 += zv;
      a2 = fmaf(zv, zv, a2);
    }
    a1 += __shfl_xor(a1, 16); a1 += __shfl_xor(a1, 32);
    a2 += __shfl_xor(a2, 16); a2 += __shfl_xor(a2, 32);
    if (lk == 0) {
      atomicAdd(&red[n * 16 + l15], a1);
      atomicAdd(&red[128 + n * 16 + l15], a2);
    }
  }
  __syncthreads();
  for (int i = tid; i < 256; i += 256) atomicAdd(&statsg[256 + i], red[i]);
}

// ---------- kernel 2: fused edge GEMM, software-pipelined gathers ----------
// pipeline per wave: idx prefetched 2 tiles ahead, gs/gd gathers 1 tile ahead (regs),
// A stream 1 tile ahead (nt loads); gather consume happens a full tile after issue.
// ea loads and mge stores are non-temporal to keep g_src/g_dst LLC-resident.
__global__ __launch_bounds__(256, 2) void edge_gemm_k(
    const float* __restrict__ ea, const u16* __restrict__ Wgb,
    const float* __restrict__ Bg,
    const u16* __restrict__ g_src, const u16* __restrict__ g_dst,
    const void* __restrict__ eidx,
    u16* __restrict__ mge, float* __restrict__ statsg,
    const u32* __restrict__ flags) {
  __shared__ __align__(16) u16 mt[4][16][LSTR];
  __shared__ __align__(16) float gt[4][16][LSTR];
  int tid = threadIdx.x, lane = tid & 63, w = tid >> 6;
  int l15 = lane & 15, lk = lane >> 4;
  int el = lane >> 2, c4 = lane & 3;  // gather role: lane serves edge el, 64B chunk c4
  u32 i64 = flags[1];

  // persistent B fragments + bias
  bf16x8 bf[8][4];
#pragma unroll
  for (int n = 0; n < 8; ++n)
#pragma unroll
    for (int k = 0; k < 4; ++k)
      bf[n][k] = *(const bf16x8*)(Wgb + (size_t)(n * 16 + l15) * 128 + lk * 8 + 32 * k);
  float bias[8];
#pragma unroll
  for (int n = 0; n < 8; ++n) bias[n] = Bg[n * 16 + l15];

  float e1[8] = {0.f, 0.f, 0.f, 0.f, 0.f, 0.f, 0.f, 0.f};
  float e2[8] = {0.f, 0.f, 0.f, 0.f, 0.f, 0.f, 0.f, 0.f};

  int base = (blockIdx.x * 4 + w) * (TPW * 16);
  const float* aptr = ea + (size_t)(base + l15) * 128 + 8 * lk;

  // ---- prologue: idx t0 -> gathers t0 -> A t0 -> idx t1 ----
  int rowc = load_row(eidx, base + el, i64);
  int colc = load_col(eidx, base + el, i64);
  uv4 gsv[4], gdv[4];
#pragma unroll
  for (int it = 0; it < 4; ++it) {
    gsv[it] = *(const uv4*)(g_src + (size_t)rowc * 128 + c4 * 8 + it * 32);
    gdv[it] = *(const uv4*)(g_dst + (size_t)colc * 128 + c4 * 8 + it * 32);
  }
  fv4 tmp[8];
#pragma unroll
  for (int k = 0; k < 4; ++k) {
    tmp[2 * k]     = ntl4(aptr + 32 * k);
    tmp[2 * k + 1] = ntl4(aptr + 32 * k + 4);
  }
  bf16x8 af[4];
#pragma unroll
  for (int k = 0; k < 4; ++k) af[k] = cvt8v(tmp[2 * k], tmp[2 * k + 1]);
  int rown = load_row(eidx, base + 16 + el, i64);
  int coln = load_col(eidx, base + 16 + el, i64);

  for (int t = 0; t < TPW; ++t) {
    // (1) consume gathers for tile t (issued a full tile ago) -> gt
#pragma unroll
    for (int it = 0; it < 4; ++it) {
      int ch = c4 + 4 * it;
      const u16* sp = (const u16*)&gsv[it];
      const u16* dp = (const u16*)&gdv[it];
      fv4 lo, hi;
#pragma unroll
      for (int j = 0; j < 4; ++j) lo[j] = bf2f(sp[j]) + bf2f(dp[j]);
#pragma unroll
      for (int j = 0; j < 4; ++j) hi[j] = bf2f(sp[4 + j]) + bf2f(dp[4 + j]);
      *(fv4*)&gt[w][el][ch * 8]     = lo;
      *(fv4*)&gt[w][el][ch * 8 + 4] = hi;
    }
    // (2) A stream loads for tile t+1 (nt)
    if (t + 1 < TPW) {
      const float* anx = aptr + (size_t)(t + 1) * 16 * 128;
#pragma unroll
      for (int k = 0; k < 4; ++k) {
        tmp[2 * k]     = ntl4(anx + 32 * k);
        tmp[2 * k + 1] = ntl4(anx + 32 * k + 4);
      }
    }
    // (3) gather loads for tile t+1 (consumed next iteration)
    if (t + 1 < TPW) {
#pragma unroll
      for (int it = 0; it < 4; ++it) {
        gsv[it] = *(const uv4*)(g_src + (size_t)rown * 128 + c4 * 8 + it * 32);
        gdv[it] = *(const uv4*)(g_dst + (size_t)coln * 128 + c4 * 8 + it * 32);
      }
    }
    // (4) idx loads for tile t+2
    int rn2 = rown, cn2 = coln;
    if (t + 2 < TPW) {
      rn2 = load_row(eidx, base + (t + 2) * 16 + el, i64);
      cn2 = load_col(eidx, base + (t + 2) * 16 + el, i64);
    }
    // (5) MFMA tile t (af, bf in regs: no memory waits)
    f32x4 acc[8];
#pragma unroll
    for (int n = 0; n < 8; ++n)
      acc[n] = (f32x4){bias[n], bias[n], bias[n], bias[n]};
#pragma unroll
    for (int n = 0; n < 8; ++n)
#pragma unroll
      for (int k = 0; k < 4; ++k)
        acc[n] = __builtin_amdgcn_mfma_f32_16x16x32_bf16(af[k], bf[n][k], acc[n], 0, 0, 0);
    // (6) C-phase: m = acc + gt (f32), stats, pack -> mt, nt wide stores
#pragma unroll
    for (int n = 0; n < 8; ++n) {
#pragma unroll
      for (int r = 0; r < 4; ++r) {
        float mv = acc[n][r] + gt[w][lk * 4 + r][n * 16 + l15];
        e1[n] += mv;
        e2[n] = fmaf(mv, mv, e2[n]);
        mt[w][lk * 4 + r][n * 16 + l15] = f2bf(mv);
      }
    }
    int e0 = base + t * 16;
#pragma unroll
    for (int it = 0; it < 4; ++it) {
      int ch = c4 + 4 * it;
      uv4 v = *(const uv4*)&mt[w][el][ch * 8];
      __builtin_nontemporal_store(v, (uv4*)(mge + (size_t)(e0 + el) * 128 + ch * 8));
    }
    // (7) convert A for tile t+1; rotate idx pipeline
    if (t + 1 < TPW) {
#pragma unroll
      for (int k = 0; k < 4; ++k) af[k] = cvt8v(tmp[2 * k], tmp[2 * k + 1]);
    }
    rown = rn2; coln = cn2;
  }
  // ---- edge BN stats flush ----
#pragma unroll
  for (int n = 0; n < 8; ++n) {
    float s1 = e1[n], s2 = e2[n];
    s1 += __shfl_xor(s1, 16); s1 += __shfl_xor(s1, 32);
    s2 += __shfl_xor(s2, 16); s2 += __shfl_xor(s2, 32);
    if (lk == 0) {
      atomicAdd(&statsg[n * 16 + l15], s1);
      atomicAdd(&statsg[128 + n * 16 + l15], s2);
    }
  }
}

// ---------- kernel 3: fold BN stats ----------
__global__ void stats_fin_k(const float* __restrict__ es1, const float* __restrict__ es2,
                            const float* __restrict__ ns1, const float* __restrict__ ns2,
                            const float* __restrict__ eg_, const float* __restrict__ eb_,
                            const float* __restrict__ ng_, const float* __restrict__ nb_,
                            float* __restrict__ params) {
  int d = threadIdx.x;  // 128
  float em = es1[d] * (1.0f / NE);
  float ev = fmaxf(es2[d] * (1.0f / NE) - em * em, 0.0f);
  float esc = eg_[d] * rsqrtf(ev + 1e-5f);
  params[d] = esc;
  params[128 + d] = eb_[d] - em * esc;
  float nm = ns1[d] * (1.0f / NN);
  float nv = fmaxf(ns2[d] * (1.0f / NN) - nm * nm, 0.0f);
  float nsc = ng_[d] * rsqrtf(nv + 1e-5f);
  params[256 + d] = nsc;
  params[384 + d] = nb_[d] - nm * nsc;
}

// ---------- kernel 4: x_out = x + softplus(BN(us + (deg>0)*ud)) ----------
__global__ __launch_bounds__(256) void node_fin2_k(
    const float* __restrict__ x, const u16* __restrict__ us,
    const u16* __restrict__ ud, const u32* __restrict__ cnt,
    const float* __restrict__ params, float* __restrict__ out) {
  size_t t = (size_t)blockIdx.x * 256 + threadIdx.x;
  size_t base = t * 8;
  int d0 = (int)(base & 127);
  int n = (int)(t >> 4);
  float g = (cnt[n] != 0u) ? 1.0f : 0.0f;
  float4 xa = *(const float4*)(x + base);
  float4 xb = *(const float4*)(x + base + 4);
  float xv[8] = {xa.x, xa.y, xa.z, xa.w, xb.x, xb.y, xb.z, xb.w};
  uint4 usv = *(const uint4*)(us + base);
  uint4 udv = *(const uint4*)(ud + base);
  const u16* up = (const u16*)&usv;
  const u16* dp = (const u16*)&udv;
  float o[8];
#pragma unroll
  for (int j = 0; j < 8; ++j) {
    float z = bf2f(up[j]) + g * bf2f(dp[j]);
    float bnv = z * params[256 + d0 + j] + params[384 + d0 + j];
    o[j] = xv[j] + splus(bnv);
  }
  *(float4*)(out + base) = make_float4(o[0], o[1], o[2], o[3]);
  *(float4*)(out + base + 4) = make_float4(o[4], o[5], o[6], o[7]);
}

// ---------- kernel 5: y_out = edge_attr + softplus(BN(mge)) — pure streaming ----------
__global__ __launch_bounds__(256) void edge_fin_k(
    const float* __restrict__ edge_attr, const u16* __restrict__ mge,
    const float* __restrict__ params, float* __restrict__ out) {
  size_t t = (size_t)blockIdx.x * 256 + threadIdx.x;
  size_t base = t * 8;
  int d0 = (int)(base & 127);
  float4 ea = *(const float4*)(edge_attr + base);
  float4 eb = *(const float4*)(edge_attr + base + 4);
  float ev[8] = {ea.x, ea.y, ea.z, ea.w, eb.x, eb.y, eb.z, eb.w};
  uint4 mv_ = *(const uint4*)(mge + base);
  const u16* mp = (const u16*)&mv_;
  float o[8];
#pragma unroll
  for (int j = 0; j < 8; ++j) {
    float m = bf2f(mp[j]);
    float bnv = m * params[d0 + j] + params[128 + d0 + j];
    o[j] = ev[j] + splus(bnv);
  }
  *(float4*)(out + base) = make_float4(o[0], o[1], o[2], o[3]);
  *(float4*)(out + base + 4) = make_float4(o[4], o[5], o[6], o[7]);
}

// ---------- launch ----------
extern "C" void kernel_launch(void* const* d_in, const int* in_sizes, int n_in,
                              void* d_out, int out_size, void* d_ws, size_t ws_size,
                              hipStream_t stream) {
  const float* x        = (const float*)d_in[0];
  const void*  eidx     = d_in[1];
  const float* edge_att = (const float*)d_in[2];
  const float* Wsg = (const float*)d_in[3];  const float* bsg = (const float*)d_in[4];
  const float* Wdg = (const float*)d_in[5];  const float* bdg = (const float*)d_in[6];
  const float* Weg = (const float*)d_in[7];  const float* beg = (const float*)d_in[8];
  const float* Wsu = (const float*)d_in[9];  const float* bsu = (const float*)d_in[10];
  const float* Wdu = (const float*)d_in[11]; const float* bdu = (const float*)d_in[12];
  const float* bng = (const float*)d_in[13]; const float* bnb = (const float*)d_in[14];
  const float* beg_g = (const float*)d_in[15]; const float* beb = (const float*)d_in[16];

  char* ws = (char*)d_ws;
  u16*   g_src  = (u16*)(ws + 0);              // NN*128 bf16
  u16*   g_dst  = (u16*)(ws + 10240000);
  u16*   u_dst  = (u16*)(ws + 20480000);
  u16*   u_src  = (u16*)(ws + 30720000);
  float* stats  = (float*)(ws + 40960000);     // es1,es2,ns1,ns2,params (1024 f32)
  u32*   flags  = (u32*)(ws + 40964096);
  u16*   wbuf   = (u16*)(ws + 40968192);       // 5*16384 bf16
  u32*   cnt    = (u32*)(ws + 41132032);       // 40000 u32 (in-degree)
  u16*   mge    = (u16*)(ws + 41292032);       // NE*128 bf16 (full gate pre-activation)

  hipMemsetAsync(stats, 0, 4096, stream);
  hipMemsetAsync(cnt, 0, 160000, stream);

  sniff_k<<<1, 64, 0, stream>>>((const u32*)bng, (const u32*)eidx, flags);
  wconv5_k<<<dim3(64, 5), 256, 0, stream>>>(Wsg, Wdg, Wdu, Wsu, Weg, wbuf);
  hist_k<<<NE / 256, 256, 0, stream>>>(eidx, cnt, flags);
  node_gemm_k<<<NN / 64, 256, 0, stream>>>(x, wbuf, bsg, bdg, bdu, bsu, cnt,
                                           g_src, g_dst, u_dst, u_src, stats);
  edge_gemm_k<<<NE / (64 * TPW), 256, 0, stream>>>(edge_att, wbuf + 4 * 16384, beg,
                                                   g_src, g_dst, eidx,
                                                   mge, stats, flags);
  stats_fin_k<<<1, 128, 0, stream>>>(stats, stats + 128, stats + 256, stats + 384,
                                     beg_g, beb, bng, bnb, stats + 512);
  node_fin2_k<<<(NN * 128) / 2048, 256, 0, stream>>>(x, u_src, u_dst, cnt,
                                                     stats + 512, (float*)d_out);
  edge_fin_k<<<(NE * 128) / 2048, 256, 0, stream>>>(edge_att, mge, stats + 512,
                                                    (float*)d_out + (size_t)NN * 128);
}

// Round 4
// 473.047 us; speedup vs baseline: 1.2338x; 1.2338x over previous
//
#include <hip/hip_runtime.h>

#define NN 40000
#define NE 640000
// D = 128; f32 inputs, indices sniffed i32/i64 at runtime

typedef unsigned short u16;
typedef unsigned int u32;
typedef __attribute__((ext_vector_type(4))) float f32x4;
typedef __attribute__((ext_vector_type(4))) float fv4;
typedef __attribute__((ext_vector_type(4))) u32 uv4;
typedef __attribute__((ext_vector_type(8))) __bf16 bf16x8;

#define LSTR 132  // LDS row stride in elements (gt: f32, mt: u16)
#define TPW 8     // tiles (16 edges) per wave in edge_gemm

__device__ __forceinline__ float bf2f(u16 u) { return __uint_as_float(((u32)u) << 16); }
__device__ __forceinline__ u16 f2bf(float f) {
  u32 u = __float_as_uint(f);
  u32 r = 0x7fffu + ((u >> 16) & 1u);
  return (u16)((u + r) >> 16);
}
__device__ __forceinline__ float splus(float v) {
  return fmaxf(v, 0.0f) + __logf(1.0f + __expf(-fabsf(v)));
}

// ---------- sniff index dtype ----------
__global__ void sniff_k(const u32* __restrict__ gamma, const u32* __restrict__ eidx,
                        u32* __restrict__ flags) {
  if (threadIdx.x == 0) {
    flags[0] = (gamma[0] == 0x3F803F80u) ? 1u : 0u;
    u32 odd = eidx[1] | eidx[3] | eidx[5] | eidx[7] |
              eidx[9] | eidx[11] | eidx[13] | eidx[15];
    flags[1] = (odd == 0u) ? 1u : 0u;  // int64 indices?
  }
}

__device__ __forceinline__ int load_col(const void* eidx, int e, u32 i64) {
  int nc = i64 ? (int)((const u32*)eidx)[2 * ((size_t)NE + e)]
               : ((const int*)eidx)[NE + e];
  return min(max(nc, 0), NN - 1);
}
__device__ __forceinline__ int load_row(const void* eidx, int e, u32 i64) {
  int nr = i64 ? (int)((const u32*)eidx)[2 * (size_t)e]
               : ((const int*)eidx)[e];
  return min(max(nr, 0), NN - 1);
}

// ---------- weights f32 -> bf16 (sg, dg, du, su, eg) ----------
__global__ __launch_bounds__(256) void wconv5_k(
    const float* __restrict__ W0, const float* __restrict__ W1,
    const float* __restrict__ W2, const float* __restrict__ W3,
    const float* __restrict__ W4, u16* __restrict__ out) {
  int i = blockIdx.x * 256 + threadIdx.x;
  int mtx = blockIdx.y;
  const float* W = (mtx == 0) ? W0 : (mtx == 1) ? W1 : (mtx == 2) ? W2
                 : (mtx == 3) ? W3 : W4;
  out[mtx * 16384 + i] = f2bf(W[i]);
}

// ---------- in-degree histogram (deg==0 guard for the gate factor) ----------
__global__ __launch_bounds__(256) void hist_k(const void* __restrict__ eidx,
                                              u32* __restrict__ cnt,
                                              const u32* __restrict__ flags) {
  int e = blockIdx.x * 256 + threadIdx.x;
  atomicAdd(&cnt[load_col(eidx, e, flags[1])], 1u);
}

// ---------- MFMA helpers ----------
__device__ __forceinline__ bf16x8 a_frag(const float* __restrict__ row, int kbase) {
  float4 f0 = *(const float4*)(row + kbase);
  float4 f1 = *(const float4*)(row + kbase + 4);
  bf16x8 a;
  a[0] = (__bf16)f0.x; a[1] = (__bf16)f0.y; a[2] = (__bf16)f0.z; a[3] = (__bf16)f0.w;
  a[4] = (__bf16)f1.x; a[5] = (__bf16)f1.y; a[6] = (__bf16)f1.z; a[7] = (__bf16)f1.w;
  return a;
}

__device__ __forceinline__ bf16x8 cvt8v(fv4 a, fv4 b) {
  bf16x8 r;
  r[0] = (__bf16)a[0]; r[1] = (__bf16)a[1]; r[2] = (__bf16)a[2]; r[3] = (__bf16)a[3];
  r[4] = (__bf16)b[0]; r[5] = (__bf16)b[1]; r[6] = (__bf16)b[2]; r[7] = (__bf16)b[3];
  return r;
}

__device__ __forceinline__ void gemm16(const bf16x8 af[4], const u16* __restrict__ Wb,
                                       const float* __restrict__ bias, int lane,
                                       f32x4 acc[8]) {
  int l15 = lane & 15, lk = lane >> 4;
#pragma unroll
  for (int n = 0; n < 8; ++n) {
    float bv = bias[n * 16 + l15];
    acc[n] = (f32x4){bv, bv, bv, bv};
  }
#pragma unroll
  for (int n = 0; n < 8; ++n) {
    const u16* bp = Wb + (size_t)(n * 16 + l15) * 128 + lk * 8;
#pragma unroll
    for (int k = 0; k < 4; ++k) {
      bf16x8 b = *(const bf16x8*)(bp + 32 * k);
      acc[n] = __builtin_amdgcn_mfma_f32_16x16x32_bf16(af[k], b, acc[n], 0, 0, 0);
    }
  }
}

__device__ __forceinline__ void store_tile(u16* __restrict__ out, int m0, int lane,
                                           const f32x4 acc[8]) {
  int l15 = lane & 15, lk = lane >> 4;
#pragma unroll
  for (int n = 0; n < 8; ++n)
#pragma unroll
    for (int r = 0; r < 4; ++r)
      out[(size_t)(m0 + lk * 4 + r) * 128 + n * 16 + l15] = f2bf(acc[n][r]);
}

// ---------- kernel 1: 4 node GEMMs via MFMA + fused node BN stats ----------
__global__ __launch_bounds__(256) void node_gemm_k(
    const float* __restrict__ x, const u16* __restrict__ Wb,
    const float* __restrict__ B0, const float* __restrict__ B1,
    const float* __restrict__ B2, const float* __restrict__ B3,
    const u32* __restrict__ cnt,
    u16* __restrict__ o0, u16* __restrict__ o1,
    u16* __restrict__ o2, u16* __restrict__ o3,
    float* __restrict__ statsg) {
  __shared__ float red[256];
  int tid = threadIdx.x, lane = tid & 63, w = tid >> 6;
  for (int i = tid; i < 256; i += 256) red[i] = 0.f;
  __syncthreads();
  int m0 = blockIdx.x * 64 + w * 16;
  int l15 = lane & 15, lk = lane >> 4;
  const float* arow = x + (size_t)(m0 + l15) * 128;
  bf16x8 af[4];
#pragma unroll
  for (int k = 0; k < 4; ++k) af[k] = a_frag(arow, 32 * k + 8 * lk);
  f32x4 acc[8], accd[8];
  gemm16(af, Wb + 0 * 16384, B0, lane, acc);  store_tile(o0, m0, lane, acc);
  gemm16(af, Wb + 1 * 16384, B1, lane, acc);  store_tile(o1, m0, lane, acc);
  gemm16(af, Wb + 2 * 16384, B2, lane, accd); store_tile(o2, m0, lane, accd);
  gemm16(af, Wb + 3 * 16384, B3, lane, acc);  store_tile(o3, m0, lane, acc);
  float g[4];
#pragma unroll
  for (int r = 0; r < 4; ++r) g[r] = (cnt[m0 + lk * 4 + r] != 0u) ? 1.0f : 0.0f;
#pragma unroll
  for (int n = 0; n < 8; ++n) {
    float a1 = 0.f, a2 = 0.f;
#pragma unroll
    for (int r = 0; r < 4; ++r) {
      float zv = acc[n][r] + g[r] * accd[n][r];
      a1 += zv;
      a2 = fmaf(zv, zv, a2);
    }
    a1 += __shfl_xor(a1, 16); a1 += __shfl_xor(a1, 32);
    a2 += __shfl_xor(a2, 16); a2 += __shfl_xor(a2, 32);
    if (lk == 0) {
      atomicAdd(&red[n * 16 + l15], a1);
      atomicAdd(&red[128 + n * 16 + l15], a2);
    }
  }
  __syncthreads();
  for (int i = tid; i < 256; i += 256) atomicAdd(&statsg[256 + i], red[i]);
}

// ---------- kernel 2: fused edge GEMM; B weights in swizzled LDS (no reg spill) ----------
// W_lds: 16B-group swizzle g' = g ^ ((row&7)<<1) -> conflict-free ds_read_b128 B-frags.
// gt (f32 gather tile) and mt (bf16 out tile) share one per-wave LDS buffer:
// C-phase reads ALL gt values to regs first, sched_barrier, then writes mt (alias-safe).
__global__ __launch_bounds__(256, 2) void edge_gemm_k(
    const float* __restrict__ ea, const u16* __restrict__ Wgb,
    const float* __restrict__ Bg,
    const u16* __restrict__ g_src, const u16* __restrict__ g_dst,
    const void* __restrict__ eidx,
    u16* __restrict__ mge, float* __restrict__ statsg,
    const u32* __restrict__ flags) {
  __shared__ __align__(16) char gbuf[4][16 * LSTR * 4];  // per-wave gt/mt union
  __shared__ __align__(16) u16 Wl[16384];                // 32KB swizzled weights
  int tid = threadIdx.x, lane = tid & 63, w = tid >> 6;
  int l15 = lane & 15, lk = lane >> 4;
  int el = lane >> 2, c4 = lane & 3;  // gather/store role
  u32 i64 = flags[1];

  // cooperative W load with 16B-group swizzle (u32 granularity)
  {
    const u32* Wg32 = (const u32*)Wgb;
    u32* Wl32 = (u32*)Wl;
#pragma unroll
    for (int j = 0; j < 32; ++j) {
      int i2 = tid + 256 * j;          // 0..8191
      int r = i2 >> 6, c2 = i2 & 63;   // row, u32-col
      int g = c2 >> 2, win = c2 & 3;   // 16B group, word-in-group
      Wl32[r * 64 + (((g ^ ((r & 7) << 1)) << 2) | win)] = Wg32[i2];
    }
  }
  __syncthreads();

  float* gt = (float*)gbuf[w];  // [16][LSTR] f32
  u16*   mt = (u16*)gbuf[w];    // [16][LSTR] u16 (aliases gt rows 0..7)
  int sw = (l15 & 7) << 1;

  float bias[8];
#pragma unroll
  for (int n = 0; n < 8; ++n) bias[n] = Bg[n * 16 + l15];

  float e1[8] = {0.f, 0.f, 0.f, 0.f, 0.f, 0.f, 0.f, 0.f};
  float e2[8] = {0.f, 0.f, 0.f, 0.f, 0.f, 0.f, 0.f, 0.f};

  int base = (blockIdx.x * 4 + w) * (TPW * 16);
  const float* aptr = ea + (size_t)(base + l15) * 128 + 8 * lk;

  // prologue: load + convert A tile 0
  fv4 tmp[8];
#pragma unroll
  for (int k = 0; k < 4; ++k) {
    tmp[2 * k]     = *(const fv4*)(aptr + 32 * k);
    tmp[2 * k + 1] = *(const fv4*)(aptr + 32 * k + 4);
  }
  bf16x8 af[4];
#pragma unroll
  for (int k = 0; k < 4; ++k) af[k] = cvt8v(tmp[2 * k], tmp[2 * k + 1]);

  for (int t = 0; t < TPW; ++t) {
    int e0 = base + t * 16;
    // ---- gather gs[row]+gd[col] for this tile -> gt (f32) ----
    int eg = e0 + el;
    int grow = load_row(eidx, eg, i64);
    int gcol = load_col(eidx, eg, i64);
#pragma unroll
    for (int it = 0; it < 4; ++it) {
      uv4 gsv = *(const uv4*)(g_src + (size_t)grow * 128 + c4 * 8 + it * 32);
      uv4 gdv = *(const uv4*)(g_dst + (size_t)gcol * 128 + c4 * 8 + it * 32);
      const u16* sp = (const u16*)&gsv;
      const u16* dp = (const u16*)&gdv;
      fv4 lo, hi;
#pragma unroll
      for (int j = 0; j < 4; ++j) lo[j] = bf2f(sp[j]) + bf2f(dp[j]);
#pragma unroll
      for (int j = 0; j < 4; ++j) hi[j] = bf2f(sp[4 + j]) + bf2f(dp[4 + j]);
      int ch = c4 + 4 * it;
      *(fv4*)(gt + el * LSTR + ch * 8)     = lo;
      *(fv4*)(gt + el * LSTR + ch * 8 + 4) = hi;
    }
    // ---- issue A loads for tile t+1 ----
    if (t + 1 < TPW) {
      const float* anx = aptr + (size_t)(t + 1) * 16 * 128;
#pragma unroll
      for (int k = 0; k < 4; ++k) {
        tmp[2 * k]     = *(const fv4*)(anx + 32 * k);
        tmp[2 * k + 1] = *(const fv4*)(anx + 32 * k + 4);
      }
    }
    // ---- MFMA tile t: B frags from swizzled LDS ----
    f32x4 acc[8];
#pragma unroll
    for (int n = 0; n < 8; ++n)
      acc[n] = (f32x4){bias[n], bias[n], bias[n], bias[n]};
#pragma unroll
    for (int n = 0; n < 8; ++n)
#pragma unroll
      for (int k = 0; k < 4; ++k) {
        bf16x8 b = *(const bf16x8*)(Wl + ((n * 16 + l15) << 7) +
                                    (((lk + 4 * k) ^ sw) << 3));
        acc[n] = __builtin_amdgcn_mfma_f32_16x16x32_bf16(af[k], b, acc[n], 0, 0, 0);
      }
    // ---- C-phase: read ALL gt -> regs, then m = acc+g, stats, write mt (alias) ----
    float g32[8][4];
#pragma unroll
    for (int n = 0; n < 8; ++n)
#pragma unroll
      for (int r = 0; r < 4; ++r)
        g32[n][r] = gt[(lk * 4 + r) * LSTR + n * 16 + l15];
    __builtin_amdgcn_sched_barrier(0);
#pragma unroll
    for (int n = 0; n < 8; ++n)
#pragma unroll
      for (int r = 0; r < 4; ++r) {
        float mv = acc[n][r] + g32[n][r];
        e1[n] += mv;
        e2[n] = fmaf(mv, mv, e2[n]);
        mt[(lk * 4 + r) * LSTR + n * 16 + l15] = f2bf(mv);
      }
    // ---- convert A for tile t+1 ----
    if (t + 1 < TPW) {
#pragma unroll
      for (int k = 0; k < 4; ++k) af[k] = cvt8v(tmp[2 * k], tmp[2 * k + 1]);
    }
    // ---- wide stores of m to mge ----
#pragma unroll
    for (int it = 0; it < 4; ++it) {
      int ch = c4 + 4 * it;
      uint4 v = *(const uint4*)(mt + el * LSTR + ch * 8);
      *(uint4*)(mge + (size_t)(e0 + el) * 128 + ch * 8) = v;
    }
  }
  // ---- edge BN stats flush ----
#pragma unroll
  for (int n = 0; n < 8; ++n) {
    float s1 = e1[n], s2 = e2[n];
    s1 += __shfl_xor(s1, 16); s1 += __shfl_xor(s1, 32);
    s2 += __shfl_xor(s2, 16); s2 += __shfl_xor(s2, 32);
    if (lk == 0) {
      atomicAdd(&statsg[n * 16 + l15], s1);
      atomicAdd(&statsg[128 + n * 16 + l15], s2);
    }
  }
}

// ---------- kernel 3: fold BN stats ----------
__global__ void stats_fin_k(const float* __restrict__ es1, const float* __restrict__ es2,
                            const float* __restrict__ ns1, const float* __restrict__ ns2,
                            const float* __restrict__ eg_, const float* __restrict__ eb_,
                            const float* __restrict__ ng_, const float* __restrict__ nb_,
                            float* __restrict__ params) {
  int d = threadIdx.x;  // 128
  float em = es1[d] * (1.0f / NE);
  float ev = fmaxf(es2[d] * (1.0f / NE) - em * em, 0.0f);
  float esc = eg_[d] * rsqrtf(ev + 1e-5f);
  params[d] = esc;
  params[128 + d] = eb_[d] - em * esc;
  float nm = ns1[d] * (1.0f / NN);
  float nv = fmaxf(ns2[d] * (1.0f / NN) - nm * nm, 0.0f);
  float nsc = ng_[d] * rsqrtf(nv + 1e-5f);
  params[256 + d] = nsc;
  params[384 + d] = nb_[d] - nm * nsc;
}

// ---------- kernel 4: x_out = x + softplus(BN(us + (deg>0)*ud)) ----------
__global__ __launch_bounds__(256) void node_fin2_k(
    const float* __restrict__ x, const u16* __restrict__ us,
    const u16* __restrict__ ud, const u32* __restrict__ cnt,
    const float* __restrict__ params, float* __restrict__ out) {
  size_t t = (size_t)blockIdx.x * 256 + threadIdx.x;
  size_t base = t * 8;
  int d0 = (int)(base & 127);
  int n = (int)(t >> 4);
  float g = (cnt[n] != 0u) ? 1.0f : 0.0f;
  float4 xa = *(const float4*)(x + base);
  float4 xb = *(const float4*)(x + base + 4);
  float xv[8] = {xa.x, xa.y, xa.z, xa.w, xb.x, xb.y, xb.z, xb.w};
  uint4 usv = *(const uint4*)(us + base);
  uint4 udv = *(const uint4*)(ud + base);
  const u16* up = (const u16*)&usv;
  const u16* dp = (const u16*)&udv;
  float o[8];
#pragma unroll
  for (int j = 0; j < 8; ++j) {
    float z = bf2f(up[j]) + g * bf2f(dp[j]);
    float bnv = z * params[256 + d0 + j] + params[384 + d0 + j];
    o[j] = xv[j] + splus(bnv);
  }
  *(float4*)(out + base) = make_float4(o[0], o[1], o[2], o[3]);
  *(float4*)(out + base + 4) = make_float4(o[4], o[5], o[6], o[7]);
}

// ---------- kernel 5: y_out = edge_attr + softplus(BN(mge)) — pure streaming ----------
__global__ __launch_bounds__(256) void edge_fin_k(
    const float* __restrict__ edge_attr, const u16* __restrict__ mge,
    const float* __restrict__ params, float* __restrict__ out) {
  size_t t = (size_t)blockIdx.x * 256 + threadIdx.x;
  size_t base = t * 8;
  int d0 = (int)(base & 127);
  float4 ea = *(const float4*)(edge_attr + base);
  float4 eb = *(const float4*)(edge_attr + base + 4);
  float ev[8] = {ea.x, ea.y, ea.z, ea.w, eb.x, eb.y, eb.z, eb.w};
  uint4 mv_ = *(const uint4*)(mge + base);
  const u16* mp = (const u16*)&mv_;
  float o[8];
#pragma unroll
  for (int j = 0; j < 8; ++j) {
    float m = bf2f(mp[j]);
    float bnv = m * params[d0 + j] + params[128 + d0 + j];
    o[j] = ev[j] + splus(bnv);
  }
  *(float4*)(out + base) = make_float4(o[0], o[1], o[2], o[3]);
  *(float4*)(out + base + 4) = make_float4(o[4], o[5], o[6], o[7]);
}

// ---------- launch ----------
extern "C" void kernel_launch(void* const* d_in, const int* in_sizes, int n_in,
                              void* d_out, int out_size, void* d_ws, size_t ws_size,
                              hipStream_t stream) {
  const float* x        = (const float*)d_in[0];
  const void*  eidx     = d_in[1];
  const float* edge_att = (const float*)d_in[2];
  const float* Wsg = (const float*)d_in[3];  const float* bsg = (const float*)d_in[4];
  const float* Wdg = (const float*)d_in[5];  const float* bdg = (const float*)d_in[6];
  const float* Weg = (const float*)d_in[7];  const float* beg = (const float*)d_in[8];
  const float* Wsu = (const float*)d_in[9];  const float* bsu = (const float*)d_in[10];
  const float* Wdu = (const float*)d_in[11]; const float* bdu = (const float*)d_in[12];
  const float* bng = (const float*)d_in[13]; const float* bnb = (const float*)d_in[14];
  const float* beg_g = (const float*)d_in[15]; const float* beb = (const float*)d_in[16];

  char* ws = (char*)d_ws;
  u16*   g_src  = (u16*)(ws + 0);              // NN*128 bf16
  u16*   g_dst  = (u16*)(ws + 10240000);
  u16*   u_dst  = (u16*)(ws + 20480000);
  u16*   u_src  = (u16*)(ws + 30720000);
  float* stats  = (float*)(ws + 40960000);     // es1,es2,ns1,ns2,params (1024 f32)
  u32*   flags  = (u32*)(ws + 40964096);
  u16*   wbuf   = (u16*)(ws + 40968192);       // 5*16384 bf16
  u32*   cnt    = (u32*)(ws + 41132032);       // 40000 u32 (in-degree)
  u16*   mge    = (u16*)(ws + 41292032);       // NE*128 bf16 (full gate pre-activation)

  hipMemsetAsync(stats, 0, 4096, stream);
  hipMemsetAsync(cnt, 0, 160000, stream);

  sniff_k<<<1, 64, 0, stream>>>((const u32*)bng, (const u32*)eidx, flags);
  wconv5_k<<<dim3(64, 5), 256, 0, stream>>>(Wsg, Wdg, Wdu, Wsu, Weg, wbuf);
  hist_k<<<NE / 256, 256, 0, stream>>>(eidx, cnt, flags);
  node_gemm_k<<<NN / 64, 256, 0, stream>>>(x, wbuf, bsg, bdg, bdu, bsu, cnt,
                                           g_src, g_dst, u_dst, u_src, stats);
  edge_gemm_k<<<NE / (64 * TPW), 256, 0, stream>>>(edge_att, wbuf + 4 * 16384, beg,
                                                   g_src, g_dst, eidx,
                                                   mge, stats, flags);
  stats_fin_k<<<1, 128, 0, stream>>>(stats, stats + 128, stats + 256, stats + 384,
                                     beg_g, beb, bng, bnb, stats + 512);
  node_fin2_k<<<(NN * 128) / 2048, 256, 0, stream>>>(x, u_src, u_dst, cnt,
                                                     stats + 512, (float*)d_out);
  edge_fin_k<<<(NE * 128) / 2048, 256, 0, stream>>>(edge_att, mge, stats + 512,
                                                    (float*)d_out + (size_t)NN * 128);
}